// Round 5
// baseline (67.183 us; speedup 1.0000x reference)
//
#include <hip/hip_runtime.h>
#include <math.h>

#define DEV __device__ __forceinline__

struct F3 { float x, y, z; };

DEV F3 mkf3(float x, float y, float z){ F3 r; r.x=x; r.y=y; r.z=z; return r; }
DEV F3 f3add(F3 a, F3 b){ return mkf3(a.x+b.x, a.y+b.y, a.z+b.z); }
DEV F3 f3sub(F3 a, F3 b){ return mkf3(a.x-b.x, a.y-b.y, a.z-b.z); }
DEV F3 f3scale(F3 a, float s){ return mkf3(a.x*s, a.y*s, a.z*s); }
DEV float f3dot(F3 a, F3 b){ return a.x*b.x + a.y*b.y + a.z*b.z; }
DEV F3 f3cross(F3 a, F3 b){
  return mkf3(a.y*b.z - a.z*b.y, a.z*b.x - a.x*b.z, a.x*b.y - a.y*b.x);
}
// reference: v / sqrt(max(sum(v*v), 1e-6)); fallback branch is dead
DEV F3 f3dir(F3 v){
  float ss = f3dot(v, v);
  float inv = 1.0f / sqrtf(fmaxf(ss, 1e-6f));
  return f3scale(v, inv);
}
DEV float fast_silu(float x){
  return x * __builtin_amdgcn_rcpf(1.0f + __expf(-x));
}
DEV float fast_sigmoid(float x){
  return __builtin_amdgcn_rcpf(1.0f + __expf(-x));
}

// ---------------------------------------------------------------------------
// Kernel A: per-node frames [N,3,3] + delta_local [N,3].
// Last block additionally packs+prescales the edge-MLP weights:
//   wpk[j*8+{0..5}] = {-log2e*W1[0..3][j], -log2e*b1[j], -ln2*w2[j]}
// ---------------------------------------------------------------------------
__global__ void frames_kernel(const float* __restrict__ xc,
                              const float* __restrict__ xt,
                              float* __restrict__ frames,
                              float* __restrict__ dl,
                              const float* __restrict__ W_eg1,
                              const float* __restrict__ b_eg1,
                              const float* __restrict__ w_eg2,
                              float* __restrict__ wpk, int N)
{
  if (blockIdx.x == (unsigned)(N / 256)) {   // weight-pack block
    int j = threadIdx.x;
    if (j < 128) {
      const float nl2e = -1.44269504088896340736f;  // -log2(e)
      const float nln2 = -0.69314718055994530942f;  // -ln(2)
      wpk[j*8+0] = nl2e * W_eg1[j];
      wpk[j*8+1] = nl2e * W_eg1[128 + j];
      wpk[j*8+2] = nl2e * W_eg1[256 + j];
      wpk[j*8+3] = nl2e * W_eg1[384 + j];
      wpk[j*8+4] = nl2e * b_eg1[j];
      wpk[j*8+5] = nln2 * w_eg2[j];
      wpk[j*8+6] = 0.f; wpk[j*8+7] = 0.f;
    }
    return;
  }
  int n = blockIdx.x * blockDim.x + threadIdx.x;
  if (n >= N) return;
  int pn = (n > 0) ? n - 1 : 0;       // prev = d[max(n-1,0)]
  int qn = (n < N - 1) ? n : N - 2;   // nxt  = d[min(n,N-2)]
  F3 prev = mkf3(xc[(pn+1)*3+0]-xc[pn*3+0], xc[(pn+1)*3+1]-xc[pn*3+1], xc[(pn+1)*3+2]-xc[pn*3+2]);
  F3 nxt  = mkf3(xc[(qn+1)*3+0]-xc[qn*3+0], xc[(qn+1)*3+1]-xc[qn*3+1], xc[(qn+1)*3+2]-xc[qn*3+2]);

  F3 tangent = f3dir(f3add(prev, nxt));
  F3 curv    = f3dir(f3sub(nxt, prev));
  float ct   = f3dot(curv, tangent);
  F3 ay      = f3dir(f3sub(curv, f3scale(tangent, ct)));
  F3 az      = f3dir(f3cross(tangent, ay));
  ay         = f3dir(f3cross(az, tangent));

  float* fr = frames + n * 9;
  fr[0] = tangent.x; fr[1] = ay.x; fr[2] = az.x;
  fr[3] = tangent.y; fr[4] = ay.y; fr[5] = az.y;
  fr[6] = tangent.z; fr[7] = ay.z; fr[8] = az.z;

  F3 delta = mkf3(xt[n*3+0]-xc[n*3+0], xt[n*3+1]-xc[n*3+1], xt[n*3+2]-xc[n*3+2]);
  dl[n*3+0] = f3dot(tangent, delta);
  dl[n*3+1] = f3dot(ay, delta);
  dl[n*3+2] = f3dot(az, delta);
}

// ---------------------------------------------------------------------------
// Kernel B: fused node MLP (layer1 + layer2 + 3 scalar heads), 4 rows/block.
// ---------------------------------------------------------------------------
__global__ __launch_bounds__(256) void node_mlp(
    const float* __restrict__ h, const float* __restrict__ dl,
    const float* __restrict__ tau,
    const float* __restrict__ W1, const float* __restrict__ b1,
    const float* __restrict__ W2, const float* __restrict__ b2,
    const float* __restrict__ w_src, const float* __restrict__ b_src,
    const float* __restrict__ w_dst, const float* __restrict__ b_dst,
    const float* __restrict__ w_ns, const float* __restrict__ b_ns,
    float* __restrict__ nh, float* __restrict__ srcv,
    float* __restrict__ dstv, float* __restrict__ nsv, int N)
{
  const int n0 = blockIdx.x * 4, tid = threadIdx.x;
  __shared__ float4 fA[262];       // [h, dl, t_emb] transposed, 4 rows
  __shared__ float4 fB[256];       // nh1 transposed, 4 rows
  __shared__ float red[4][4][3];   // [wave][row][head]

  {
    const float* hp = h + n0 * 256 + tid;
    fA[tid] = make_float4(hp[0], hp[256], hp[512], hp[768]);
  }
  if (tid < 6) {
    int k = 256 + tid;
    float4 v;
    if (tid < 3) {
      v = make_float4(dl[(n0+0)*3+tid], dl[(n0+1)*3+tid],
                      dl[(n0+2)*3+tid], dl[(n0+3)*3+tid]);
    } else {
      float t = tau[0];
      float s = (tid == 3) ? t : ((tid == 4) ? sinf(t) : cosf(t));
      v = make_float4(s, s, s, s);
    }
    fA[k] = v;
  }
  __syncthreads();

  // ---- layer 1 ----
  {
    float bb = b1[tid];
    float a0 = bb, a1 = bb, a2 = bb, a3 = bb;
    const float* Wp = W1 + tid;
    for (int kb = 0; kb < 256; kb += 64) {
      float w[64];
      #pragma unroll
      for (int u = 0; u < 64; ++u) w[u] = Wp[(kb + u) * 256];
      #pragma unroll
      for (int u = 0; u < 64; ++u) {
        float4 f = fA[kb + u];
        a0 = fmaf(f.x, w[u], a0); a1 = fmaf(f.y, w[u], a1);
        a2 = fmaf(f.z, w[u], a2); a3 = fmaf(f.w, w[u], a3);
      }
    }
    #pragma unroll
    for (int k = 256; k < 262; ++k) {
      float w = Wp[k * 256];
      float4 f = fA[k];
      a0 = fmaf(f.x, w, a0); a1 = fmaf(f.y, w, a1);
      a2 = fmaf(f.z, w, a2); a3 = fmaf(f.w, w, a3);
    }
    fB[tid] = make_float4(fast_silu(a0), fast_silu(a1), fast_silu(a2), fast_silu(a3));
  }
  __syncthreads();

  // ---- layer 2 + heads ----
  float bb = b2[tid];
  float a0 = bb, a1 = bb, a2 = bb, a3 = bb;
  const float* Wp = W2 + tid;
  for (int kb = 0; kb < 256; kb += 64) {
    float w[64];
    #pragma unroll
    for (int u = 0; u < 64; ++u) w[u] = Wp[(kb + u) * 256];
    #pragma unroll
    for (int u = 0; u < 64; ++u) {
      float4 f = fB[kb + u];
      a0 = fmaf(f.x, w[u], a0); a1 = fmaf(f.y, w[u], a1);
      a2 = fmaf(f.z, w[u], a2); a3 = fmaf(f.w, w[u], a3);
    }
  }

  const float wsv = w_src[tid], wdv = w_dst[tid], wnv = w_ns[tid];
  const int wave = tid >> 6, lane = tid & 63;
  float va[4] = {fast_silu(a0), fast_silu(a1), fast_silu(a2), fast_silu(a3)};
  #pragma unroll
  for (int r = 0; r < 4; ++r) {
    nh[(n0 + r) * 256 + tid] = va[r];
    float ps = va[r] * wsv, pd = va[r] * wdv, pn = va[r] * wnv;
    for (int off = 32; off; off >>= 1) {
      ps += __shfl_down(ps, off);
      pd += __shfl_down(pd, off);
      pn += __shfl_down(pn, off);
    }
    if (lane == 0) { red[wave][r][0] = ps; red[wave][r][1] = pd; red[wave][r][2] = pn; }
  }
  __syncthreads();
  if (tid < 4) {
    int r = tid;
    float s0 = 0.f, s1 = 0.f, s2 = 0.f;
    #pragma unroll
    for (int w = 0; w < 4; ++w) { s0 += red[w][r][0]; s1 += red[w][r][1]; s2 += red[w][r][2]; }
    srcv[n0 + r] = s0 + b_src[0];
    dstv[n0 + r] = s1 + b_dst[0];
    nsv[n0 + r]  = fast_sigmoid(s2 + b_ns[0]);
  }
}

// ---------------------------------------------------------------------------
// Kernel D: fused edge MLP + partial softmax + partial aggregation.
// 2 blocks per row (grid 2N); block handles 512 edges (2/thread, 4 waves).
// Weights pre-packed/pre-scaled in wpk -> two uniform s_load_dwordx4 per j;
// inner loop: 14 VALU + 4 trans per j for 2 edges, zero LDS.
// Emits per-block partial {max, Z, a0, a1, a2} (combined in out_mlp).
// ---------------------------------------------------------------------------
__global__ __launch_bounds__(256, 8) void edge_softmax(
    const float* __restrict__ x_t, const float* __restrict__ frames,
    const float* __restrict__ srcv, const float* __restrict__ dstv,
    const float* __restrict__ nsv,
    const float* __restrict__ wpk, const float* __restrict__ b_eg2,
    float* __restrict__ part, int N)
{
  const int bid = blockIdx.x;
  const int n = bid >> 1, half = bid & 1;
  const int tid = threadIdx.x;
  __shared__ float redmax[4];
  __shared__ float red[4][4];

  // row-uniform data -> scalar loads
  const float f0 = frames[n*9+0], f1 = frames[n*9+1], f2 = frames[n*9+2],
              f3_ = frames[n*9+3], f4 = frames[n*9+4], f5 = frames[n*9+5],
              f6 = frames[n*9+6], f7 = frames[n*9+7], f8 = frames[n*9+8];
  const float x0 = x_t[n*3+0], x1 = x_t[n*3+1], x2 = x_t[n*3+2];
  const float sn = srcv[n];
  const float b2v = b_eg2[0];
  const int m0i = half * 512 + tid;

  // ---- phase 0: per-edge raw rel_local + dist ----
  float r0[2], r1[2], r2[2], dd[2];
  #pragma unroll
  for (int e = 0; e < 2; ++e) {
    const int m = m0i + e * 256;
    float rx = x_t[m * 3 + 0] - x0;
    float ry = x_t[m * 3 + 1] - x1;
    float rz = x_t[m * 3 + 2] - x2;
    r0[e] = f0 * rx + f3_ * ry + f6 * rz;
    r1[e] = f1 * rx + f4 * ry + f7 * rz;
    r2[e] = f2 * rx + f5 * ry + f8 * rz;
    dd[e] = sqrtf(r0[e]*r0[e] + r1[e]*r1[e] + r2[e]*r2[e]);
  }

  // ---- phase 1: edge-MLP logits; packed weights via s_load_dwordx4 ----
  const float4* wp4 = (const float4*)wpk;
  float acc[2] = {0.f, 0.f};
  #pragma unroll 8
  for (int j = 0; j < 128; ++j) {
    const float4 wa = wp4[2*j];       // {wx, wy, wz, wd} * -log2e
    const float4 wb = wp4[2*j+1];     // {b * -log2e, w2 * -ln2, 0, 0}
    #pragma unroll
    for (int e = 0; e < 2; ++e) {
      float tp = fmaf(wa.w, dd[e], wb.x);
      tp = fmaf(wa.z, r2[e], tp);
      tp = fmaf(wa.y, r1[e], tp);
      tp = fmaf(wa.x, r0[e], tp);
      float q  = tp * wb.y;                          // w2s * tp (hides trans latency)
      float ex = __builtin_amdgcn_exp2f(tp);         // = exp(-t)
      float sg = __builtin_amdgcn_rcpf(1.0f + ex);   // sigma(t)
      acc[e] = fmaf(q, sg, acc[e]);                  // += w2 * t * sigma(t)
    }
  }

  float l[2];
  float lmax = -3.4e38f;
  #pragma unroll
  for (int e = 0; e < 2; ++e) {
    const int m = m0i + e * 256;
    float lg = sn + dstv[m] + b2v + acc[e];
    if (m == n) lg = -10000.0f;
    l[e] = lg;
    lmax = fmaxf(lmax, lg);
  }

  // ---- block max reduce (4 waves) ----
  for (int off = 32; off; off >>= 1) lmax = fmaxf(lmax, __shfl_down(lmax, off));
  const int wave = tid >> 6, lane = tid & 63;
  if (lane == 0) redmax[wave] = lmax;
  __syncthreads();
  const float mx = fmaxf(fmaxf(redmax[0], redmax[1]), fmaxf(redmax[2], redmax[3]));

  // ---- phase 2: partial softmax + aggregation ----
  float sum = 0.f, a0 = 0.f, a1 = 0.f, a2 = 0.f;
  #pragma unroll
  for (int e = 0; e < 2; ++e) {
    const int m = m0i + e * 256;
    float ee = __expf(l[e] - mx);     // diag underflows to 0
    sum += ee;
    float w = ee * nsv[m];
    a0 = fmaf(w, r0[e], a0);
    a1 = fmaf(w, r1[e], a1);
    a2 = fmaf(w, r2[e], a2);
  }
  for (int off = 32; off; off >>= 1) {
    sum += __shfl_down(sum, off);
    a0 += __shfl_down(a0, off);
    a1 += __shfl_down(a1, off);
    a2 += __shfl_down(a2, off);
  }
  if (lane == 0) { red[wave][0] = sum; red[wave][1] = a0; red[wave][2] = a1; red[wave][3] = a2; }
  __syncthreads();
  if (tid == 0) {
    float Z = red[0][0] + red[1][0] + red[2][0] + red[3][0];
    float m0 = red[0][1] + red[1][1] + red[2][1] + red[3][1];
    float m1 = red[0][2] + red[1][2] + red[2][2] + red[3][2];
    float m2 = red[0][3] + red[1][3] + red[2][3] + red[3][3];
    float* p = part + bid * 8;
    p[0] = mx; p[1] = Z; p[2] = m0; p[3] = m1; p[4] = m2;
  }
}

// ---------------------------------------------------------------------------
// Kernel E: combine partials -> msgs, then out MLP + 0.25*msgs + rotation
// ---------------------------------------------------------------------------
__global__ __launch_bounds__(256) void out_mlp(
    const float* __restrict__ nh, const float* __restrict__ dl,
    const float* __restrict__ part, const float* __restrict__ frames,
    const float* __restrict__ W1, const float* __restrict__ b1,
    const float* __restrict__ W2, const float* __restrict__ b2,
    float* __restrict__ out, int N)
{
  const int n0 = blockIdx.x * 4, tid = threadIdx.x;
  __shared__ float4 feat4[262];
  __shared__ float red[4][4][3];
  __shared__ float smsg[4][3];
  {
    const float* hp = nh + n0 * 256 + tid;
    feat4[tid] = make_float4(hp[0], hp[256], hp[512], hp[768]);
  }
  if (tid < 4) {   // combine the two softmax partials for row n0+tid
    int n = n0 + tid;
    const float* p0 = part + (2*n) * 8;
    const float* p1 = part + (2*n+1) * 8;
    float mx = fmaxf(p0[0], p1[0]);
    float s0 = __expf(p0[0] - mx), s1 = __expf(p1[0] - mx);
    float invZ = 1.0f / (p0[1]*s0 + p1[1]*s1);
    smsg[tid][0] = (p0[2]*s0 + p1[2]*s1) * invZ;
    smsg[tid][1] = (p0[3]*s0 + p1[3]*s1) * invZ;
    smsg[tid][2] = (p0[4]*s0 + p1[4]*s1) * invZ;
  }
  __syncthreads();
  if (tid < 6) {
    int k = 256 + tid;
    float4 v;
    if (tid < 3) {
      v = make_float4(dl[(n0+0)*3+tid], dl[(n0+1)*3+tid],
                      dl[(n0+2)*3+tid], dl[(n0+3)*3+tid]);
    } else {
      int c = tid - 3;
      v = make_float4(smsg[0][c], smsg[1][c], smsg[2][c], smsg[3][c]);
    }
    feat4[k] = v;
  }
  __syncthreads();

  float bb = b1[tid];
  float a0 = bb, a1 = bb, a2 = bb, a3 = bb;
  const float* Wp = W1 + tid;
  for (int kb = 0; kb < 256; kb += 64) {
    float w[64];
    #pragma unroll
    for (int u = 0; u < 64; ++u) w[u] = Wp[(kb + u) * 256];
    #pragma unroll
    for (int u = 0; u < 64; ++u) {
      float4 f = feat4[kb + u];
      a0 = fmaf(f.x, w[u], a0); a1 = fmaf(f.y, w[u], a1);
      a2 = fmaf(f.z, w[u], a2); a3 = fmaf(f.w, w[u], a3);
    }
  }
  #pragma unroll
  for (int k = 256; k < 262; ++k) {
    float w = Wp[k * 256];
    float4 f = feat4[k];
    a0 = fmaf(f.x, w, a0); a1 = fmaf(f.y, w, a1);
    a2 = fmaf(f.z, w, a2); a3 = fmaf(f.w, w, a3);
  }

  const float w0 = W2[tid * 3 + 0], w1 = W2[tid * 3 + 1], w2 = W2[tid * 3 + 2];
  const int wave = tid >> 6, lane = tid & 63;
  float va[4] = {fast_silu(a0), fast_silu(a1), fast_silu(a2), fast_silu(a3)};
  #pragma unroll
  for (int r = 0; r < 4; ++r) {
    float p0 = va[r] * w0, p1 = va[r] * w1, p2 = va[r] * w2;
    for (int off = 32; off; off >>= 1) {
      p0 += __shfl_down(p0, off);
      p1 += __shfl_down(p1, off);
      p2 += __shfl_down(p2, off);
    }
    if (lane == 0) { red[wave][r][0] = p0; red[wave][r][1] = p1; red[wave][r][2] = p2; }
  }
  __syncthreads();
  if (tid < 4) {
    int r = tid, n = n0 + r;
    float s0 = 0.f, s1 = 0.f, s2 = 0.f;
    #pragma unroll
    for (int w = 0; w < 4; ++w) { s0 += red[w][r][0]; s1 += red[w][r][1]; s2 += red[w][r][2]; }
    float m0 = smsg[r][0], m1 = smsg[r][1], m2 = smsg[r][2];
    float v0 = s0 + b2[0] + 0.25f * m0;
    float v1 = s1 + b2[1] + 0.25f * m1;
    float v2 = s2 + b2[2] + 0.25f * m2;
    const float* fr = frames + n * 9;
    out[n * 3 + 0] = fr[0] * v0 + fr[1] * v1 + fr[2] * v2;
    out[n * 3 + 1] = fr[3] * v0 + fr[4] * v1 + fr[5] * v2;
    out[n * 3 + 2] = fr[6] * v0 + fr[7] * v1 + fr[8] * v2;
  }
}

// ---------------------------------------------------------------------------
extern "C" void kernel_launch(void* const* d_in, const int* in_sizes, int n_in,
                              void* d_out, int out_size, void* d_ws, size_t ws_size,
                              hipStream_t stream) {
  const float* h      = (const float*)d_in[0];
  const float* x_t    = (const float*)d_in[1];
  const float* x_cond = (const float*)d_in[2];
  const float* tau    = (const float*)d_in[3];
  const float* W_np1  = (const float*)d_in[4];
  const float* b_np1  = (const float*)d_in[5];
  const float* W_np2  = (const float*)d_in[6];
  const float* b_np2  = (const float*)d_in[7];
  const float* w_src  = (const float*)d_in[8];
  const float* b_src  = (const float*)d_in[9];
  const float* w_dst  = (const float*)d_in[10];
  const float* b_dst  = (const float*)d_in[11];
  const float* w_ns   = (const float*)d_in[12];
  const float* b_ns   = (const float*)d_in[13];
  const float* W_eg1  = (const float*)d_in[14];
  const float* b_eg1  = (const float*)d_in[15];
  const float* w_eg2  = (const float*)d_in[16];
  const float* b_eg2  = (const float*)d_in[17];
  const float* W_out1 = (const float*)d_in[18];
  const float* b_out1 = (const float*)d_in[19];
  const float* W_out2 = (const float*)d_in[20];
  const float* b_out2 = (const float*)d_in[21];
  float* out = (float*)d_out;

  const int N = in_sizes[1] / 3;  // 1024

  float* ws     = (float*)d_ws;
  float* frames = ws;                 // N*9
  float* dl     = frames + N * 9;     // N*3
  float* nh     = dl + N * 3;         // N*256
  float* srcv   = nh + N * 256;       // N
  float* dstv   = srcv + N;           // N
  float* nsv    = dstv + N;           // N
  float* part   = nsv + N;            // 2N*8
  float* wpk    = part + 2 * N * 8;   // 128*8

  frames_kernel<<<N / 256 + 1, 256, 0, stream>>>(x_cond, x_t, frames, dl,
                                                 W_eg1, b_eg1, w_eg2, wpk, N);
  node_mlp<<<N / 4, 256, 0, stream>>>(h, dl, tau, W_np1, b_np1, W_np2, b_np2,
                                      w_src, b_src, w_dst, b_dst, w_ns, b_ns,
                                      nh, srcv, dstv, nsv, N);
  edge_softmax<<<2 * N, 256, 0, stream>>>(x_t, frames, srcv, dstv, nsv,
                                          wpk, b_eg2, part, N);
  out_mlp<<<N / 4, 256, 0, stream>>>(nh, dl, part, frames,
                                     W_out1, b_out1, W_out2, b_out2, out, N);
}

// Round 6
// 65.071 us; speedup vs baseline: 1.0325x; 1.0325x over previous
//
#include <hip/hip_runtime.h>
#include <math.h>

#define DEV __device__ __forceinline__

typedef float v2f __attribute__((ext_vector_type(2)));
DEV v2f splat2(float s){ return (v2f){s, s}; }

struct F3 { float x, y, z; };

DEV F3 mkf3(float x, float y, float z){ F3 r; r.x=x; r.y=y; r.z=z; return r; }
DEV F3 f3add(F3 a, F3 b){ return mkf3(a.x+b.x, a.y+b.y, a.z+b.z); }
DEV F3 f3sub(F3 a, F3 b){ return mkf3(a.x-b.x, a.y-b.y, a.z-b.z); }
DEV F3 f3scale(F3 a, float s){ return mkf3(a.x*s, a.y*s, a.z*s); }
DEV float f3dot(F3 a, F3 b){ return a.x*b.x + a.y*b.y + a.z*b.z; }
DEV F3 f3cross(F3 a, F3 b){
  return mkf3(a.y*b.z - a.z*b.y, a.z*b.x - a.x*b.z, a.x*b.y - a.y*b.x);
}
// reference: v / sqrt(max(sum(v*v), 1e-6)); fallback branch is dead
DEV F3 f3dir(F3 v){
  float ss = f3dot(v, v);
  float inv = 1.0f / sqrtf(fmaxf(ss, 1e-6f));
  return f3scale(v, inv);
}
DEV float fast_silu(float x){
  return x * __builtin_amdgcn_rcpf(1.0f + __expf(-x));
}
DEV float fast_sigmoid(float x){
  return __builtin_amdgcn_rcpf(1.0f + __expf(-x));
}

// ---------------------------------------------------------------------------
// Kernel A: per-node frames [N,3,3] + delta_local [N,3].
// Last block additionally packs+prescales the edge-MLP weights:
//   wpk[j*8+{0..5}] = {-log2e*W1[0..3][j], -log2e*b1[j], -ln2*w2[j]}
// ---------------------------------------------------------------------------
__global__ void frames_kernel(const float* __restrict__ xc,
                              const float* __restrict__ xt,
                              float* __restrict__ frames,
                              float* __restrict__ dl,
                              const float* __restrict__ W_eg1,
                              const float* __restrict__ b_eg1,
                              const float* __restrict__ w_eg2,
                              float* __restrict__ wpk, int N)
{
  if (blockIdx.x == (unsigned)(N / 256)) {   // weight-pack block
    int j = threadIdx.x;
    if (j < 128) {
      const float nl2e = -1.44269504088896340736f;  // -log2(e)
      const float nln2 = -0.69314718055994530942f;  // -ln(2)
      wpk[j*8+0] = nl2e * W_eg1[j];
      wpk[j*8+1] = nl2e * W_eg1[128 + j];
      wpk[j*8+2] = nl2e * W_eg1[256 + j];
      wpk[j*8+3] = nl2e * W_eg1[384 + j];
      wpk[j*8+4] = nl2e * b_eg1[j];
      wpk[j*8+5] = nln2 * w_eg2[j];
      wpk[j*8+6] = 0.f; wpk[j*8+7] = 0.f;
    } else if (j < 144) {
      wpk[1024 + (j - 128)] = 0.f;   // pad chunk so prefetch overrun is benign
    }
    return;
  }
  int n = blockIdx.x * blockDim.x + threadIdx.x;
  if (n >= N) return;
  int pn = (n > 0) ? n - 1 : 0;       // prev = d[max(n-1,0)]
  int qn = (n < N - 1) ? n : N - 2;   // nxt  = d[min(n,N-2)]
  F3 prev = mkf3(xc[(pn+1)*3+0]-xc[pn*3+0], xc[(pn+1)*3+1]-xc[pn*3+1], xc[(pn+1)*3+2]-xc[pn*3+2]);
  F3 nxt  = mkf3(xc[(qn+1)*3+0]-xc[qn*3+0], xc[(qn+1)*3+1]-xc[qn*3+1], xc[(qn+1)*3+2]-xc[qn*3+2]);

  F3 tangent = f3dir(f3add(prev, nxt));
  F3 curv    = f3dir(f3sub(nxt, prev));
  float ct   = f3dot(curv, tangent);
  F3 ay      = f3dir(f3sub(curv, f3scale(tangent, ct)));
  F3 az      = f3dir(f3cross(tangent, ay));
  ay         = f3dir(f3cross(az, tangent));

  float* fr = frames + n * 9;
  fr[0] = tangent.x; fr[1] = ay.x; fr[2] = az.x;
  fr[3] = tangent.y; fr[4] = ay.y; fr[5] = az.y;
  fr[6] = tangent.z; fr[7] = ay.z; fr[8] = az.z;

  F3 delta = mkf3(xt[n*3+0]-xc[n*3+0], xt[n*3+1]-xc[n*3+1], xt[n*3+2]-xc[n*3+2]);
  dl[n*3+0] = f3dot(tangent, delta);
  dl[n*3+1] = f3dot(ay, delta);
  dl[n*3+2] = f3dot(az, delta);
}

// ---------------------------------------------------------------------------
// Kernel B: fused node MLP (layer1 + layer2 + 3 scalar heads), 4 rows/block.
// ---------------------------------------------------------------------------
__global__ __launch_bounds__(256) void node_mlp(
    const float* __restrict__ h, const float* __restrict__ dl,
    const float* __restrict__ tau,
    const float* __restrict__ W1, const float* __restrict__ b1,
    const float* __restrict__ W2, const float* __restrict__ b2,
    const float* __restrict__ w_src, const float* __restrict__ b_src,
    const float* __restrict__ w_dst, const float* __restrict__ b_dst,
    const float* __restrict__ w_ns, const float* __restrict__ b_ns,
    float* __restrict__ nh, float* __restrict__ srcv,
    float* __restrict__ dstv, float* __restrict__ nsv, int N)
{
  const int n0 = blockIdx.x * 4, tid = threadIdx.x;
  __shared__ float4 fA[262];       // [h, dl, t_emb] transposed, 4 rows
  __shared__ float4 fB[256];       // nh1 transposed, 4 rows
  __shared__ float red[4][4][3];   // [wave][row][head]

  {
    const float* hp = h + n0 * 256 + tid;
    fA[tid] = make_float4(hp[0], hp[256], hp[512], hp[768]);
  }
  if (tid < 6) {
    int k = 256 + tid;
    float4 v;
    if (tid < 3) {
      v = make_float4(dl[(n0+0)*3+tid], dl[(n0+1)*3+tid],
                      dl[(n0+2)*3+tid], dl[(n0+3)*3+tid]);
    } else {
      float t = tau[0];
      float s = (tid == 3) ? t : ((tid == 4) ? sinf(t) : cosf(t));
      v = make_float4(s, s, s, s);
    }
    fA[k] = v;
  }
  __syncthreads();

  // ---- layer 1 ----
  {
    float bb = b1[tid];
    float a0 = bb, a1 = bb, a2 = bb, a3 = bb;
    const float* Wp = W1 + tid;
    for (int kb = 0; kb < 256; kb += 64) {
      float w[64];
      #pragma unroll
      for (int u = 0; u < 64; ++u) w[u] = Wp[(kb + u) * 256];
      #pragma unroll
      for (int u = 0; u < 64; ++u) {
        float4 f = fA[kb + u];
        a0 = fmaf(f.x, w[u], a0); a1 = fmaf(f.y, w[u], a1);
        a2 = fmaf(f.z, w[u], a2); a3 = fmaf(f.w, w[u], a3);
      }
    }
    #pragma unroll
    for (int k = 256; k < 262; ++k) {
      float w = Wp[k * 256];
      float4 f = fA[k];
      a0 = fmaf(f.x, w, a0); a1 = fmaf(f.y, w, a1);
      a2 = fmaf(f.z, w, a2); a3 = fmaf(f.w, w, a3);
    }
    fB[tid] = make_float4(fast_silu(a0), fast_silu(a1), fast_silu(a2), fast_silu(a3));
  }
  __syncthreads();

  // ---- layer 2 + heads ----
  float bb = b2[tid];
  float a0 = bb, a1 = bb, a2 = bb, a3 = bb;
  const float* Wp = W2 + tid;
  for (int kb = 0; kb < 256; kb += 64) {
    float w[64];
    #pragma unroll
    for (int u = 0; u < 64; ++u) w[u] = Wp[(kb + u) * 256];
    #pragma unroll
    for (int u = 0; u < 64; ++u) {
      float4 f = fB[kb + u];
      a0 = fmaf(f.x, w[u], a0); a1 = fmaf(f.y, w[u], a1);
      a2 = fmaf(f.z, w[u], a2); a3 = fmaf(f.w, w[u], a3);
    }
  }

  const float wsv = w_src[tid], wdv = w_dst[tid], wnv = w_ns[tid];
  const int wave = tid >> 6, lane = tid & 63;
  float va[4] = {fast_silu(a0), fast_silu(a1), fast_silu(a2), fast_silu(a3)};
  #pragma unroll
  for (int r = 0; r < 4; ++r) {
    nh[(n0 + r) * 256 + tid] = va[r];
    float ps = va[r] * wsv, pd = va[r] * wdv, pn = va[r] * wnv;
    for (int off = 32; off; off >>= 1) {
      ps += __shfl_down(ps, off);
      pd += __shfl_down(pd, off);
      pn += __shfl_down(pn, off);
    }
    if (lane == 0) { red[wave][r][0] = ps; red[wave][r][1] = pd; red[wave][r][2] = pn; }
  }
  __syncthreads();
  if (tid < 4) {
    int r = tid;
    float s0 = 0.f, s1 = 0.f, s2 = 0.f;
    #pragma unroll
    for (int w = 0; w < 4; ++w) { s0 += red[w][r][0]; s1 += red[w][r][1]; s2 += red[w][r][2]; }
    srcv[n0 + r] = s0 + b_src[0];
    dstv[n0 + r] = s1 + b_dst[0];
    nsv[n0 + r]  = fast_sigmoid(s2 + b_ns[0]);
  }
}

// ---------------------------------------------------------------------------
// Kernel D: fused edge MLP + softmax + aggregation.
// One block (256 thr, 4 waves) per row n; 4 edges/thread as 2 packed v2f
// chains -> v_pk_fma_f32. Weights uniform (SGPR), software-pipelined
// 1 chunk (2 j) ahead. Inner loop: 14 pk-VALU + 8 trans per j per 4 edges.
// ---------------------------------------------------------------------------
__global__ __launch_bounds__(256) void edge_softmax(
    const float* __restrict__ x_t, const float* __restrict__ frames,
    const float* __restrict__ srcv, const float* __restrict__ dstv,
    const float* __restrict__ nsv,
    const float* __restrict__ wpk, const float* __restrict__ b_eg2,
    float* __restrict__ msgs, int N)
{
  const int n = blockIdx.x, tid = threadIdx.x;
  __shared__ float redmax[4];
  __shared__ float red[4][4];

  // row-uniform data -> scalar loads
  const float f0 = frames[n*9+0], f1 = frames[n*9+1], f2 = frames[n*9+2],
              f3_ = frames[n*9+3], f4 = frames[n*9+4], f5 = frames[n*9+5],
              f6 = frames[n*9+6], f7 = frames[n*9+7], f8 = frames[n*9+8];
  const float x0 = x_t[n*3+0], x1 = x_t[n*3+1], x2 = x_t[n*3+2];
  const float sn = srcv[n];
  const float b2v = b_eg2[0];

  // ---- phase 0: 4 edges' raw rel_local + dist, packed in pairs ----
  float r0s[4], r1s[4], r2s[4], dds[4];
  #pragma unroll
  for (int e = 0; e < 4; ++e) {
    const int m = e * 256 + tid;
    float rx = x_t[m * 3 + 0] - x0;
    float ry = x_t[m * 3 + 1] - x1;
    float rz = x_t[m * 3 + 2] - x2;
    r0s[e] = f0 * rx + f3_ * ry + f6 * rz;
    r1s[e] = f1 * rx + f4 * ry + f7 * rz;
    r2s[e] = f2 * rx + f5 * ry + f8 * rz;
    dds[e] = sqrtf(r0s[e]*r0s[e] + r1s[e]*r1s[e] + r2s[e]*r2s[e]);
  }
  const v2f r0A = {r0s[0], r0s[1]}, r0B = {r0s[2], r0s[3]};
  const v2f r1A = {r1s[0], r1s[1]}, r1B = {r1s[2], r1s[3]};
  const v2f r2A = {r2s[0], r2s[1]}, r2B = {r2s[2], r2s[3]};
  const v2f ddA = {dds[0], dds[1]}, ddB = {dds[2], dds[3]};

  v2f accA = {0.f, 0.f}, accB = {0.f, 0.f};

  // ---- phase 1: edge-MLP logits; packed math + pipelined uniform loads ----
  const float4* __restrict__ wp4 = (const float4*)wpk;

#define J_STEP(WA, WB)                                                    \
  {                                                                       \
    v2f tpA = splat2(WB.x) + splat2(WA.w) * ddA;                          \
    tpA += splat2(WA.z) * r2A;                                            \
    tpA += splat2(WA.y) * r1A;                                            \
    tpA += splat2(WA.x) * r0A;                                            \
    v2f tpB = splat2(WB.x) + splat2(WA.w) * ddB;                          \
    tpB += splat2(WA.z) * r2B;                                            \
    tpB += splat2(WA.y) * r1B;                                            \
    tpB += splat2(WA.x) * r0B;                                            \
    v2f eA, eB;                                                           \
    eA.x = __builtin_amdgcn_exp2f(tpA.x); eA.y = __builtin_amdgcn_exp2f(tpA.y); \
    eB.x = __builtin_amdgcn_exp2f(tpB.x); eB.y = __builtin_amdgcn_exp2f(tpB.y); \
    v2f opA = eA + splat2(1.0f);                                          \
    v2f opB = eB + splat2(1.0f);                                          \
    v2f sgA, sgB;                                                         \
    sgA.x = __builtin_amdgcn_rcpf(opA.x); sgA.y = __builtin_amdgcn_rcpf(opA.y); \
    sgB.x = __builtin_amdgcn_rcpf(opB.x); sgB.y = __builtin_amdgcn_rcpf(opB.y); \
    accA += (splat2(WB.y) * tpA) * sgA;                                   \
    accB += (splat2(WB.y) * tpB) * sgB;                                   \
  }

  // chunk = 2 j's (4 float4 uniform loads), prefetched one chunk ahead
  float4 ca0 = wp4[0], cb0 = wp4[1], ca1 = wp4[2], cb1 = wp4[3];
  for (int c = 0; c < 64; ++c) {
    float4 na0 = wp4[(c + 1) * 4 + 0];
    float4 nb0 = wp4[(c + 1) * 4 + 1];
    float4 na1 = wp4[(c + 1) * 4 + 2];
    float4 nb1 = wp4[(c + 1) * 4 + 3];
    J_STEP(ca0, cb0)
    J_STEP(ca1, cb1)
    ca0 = na0; cb0 = nb0; ca1 = na1; cb1 = nb1;
  }
#undef J_STEP

  float l[4];
  float lmax = -3.4e38f;
  float accs[4] = {accA.x, accA.y, accB.x, accB.y};
  #pragma unroll
  for (int e = 0; e < 4; ++e) {
    const int m = e * 256 + tid;
    float lg = sn + dstv[m] + b2v + accs[e];
    if (m == n) lg = -10000.0f;
    l[e] = lg;
    lmax = fmaxf(lmax, lg);
  }

  // ---- block max reduce (4 waves) ----
  for (int off = 32; off; off >>= 1) lmax = fmaxf(lmax, __shfl_down(lmax, off));
  const int wave = tid >> 6, lane = tid & 63;
  if (lane == 0) redmax[wave] = lmax;
  __syncthreads();
  const float mx = fmaxf(fmaxf(redmax[0], redmax[1]), fmaxf(redmax[2], redmax[3]));

  // ---- phase 2: softmax + aggregation ----
  float r0all[4] = {r0A.x, r0A.y, r0B.x, r0B.y};
  float r1all[4] = {r1A.x, r1A.y, r1B.x, r1B.y};
  float r2all[4] = {r2A.x, r2A.y, r2B.x, r2B.y};
  float sum = 0.f, a0 = 0.f, a1 = 0.f, a2 = 0.f;
  #pragma unroll
  for (int e = 0; e < 4; ++e) {
    const int m = e * 256 + tid;
    float ee = __expf(l[e] - mx);     // diag underflows to 0
    sum += ee;
    float w = ee * nsv[m];
    a0 = fmaf(w, r0all[e], a0);
    a1 = fmaf(w, r1all[e], a1);
    a2 = fmaf(w, r2all[e], a2);
  }
  for (int off = 32; off; off >>= 1) {
    sum += __shfl_down(sum, off);
    a0 += __shfl_down(a0, off);
    a1 += __shfl_down(a1, off);
    a2 += __shfl_down(a2, off);
  }
  if (lane == 0) { red[wave][0] = sum; red[wave][1] = a0; red[wave][2] = a1; red[wave][3] = a2; }
  __syncthreads();
  if (tid == 0) {
    float Z  = red[0][0] + red[1][0] + red[2][0] + red[3][0];
    float m0 = red[0][1] + red[1][1] + red[2][1] + red[3][1];
    float m1 = red[0][2] + red[1][2] + red[2][2] + red[3][2];
    float m2 = red[0][3] + red[1][3] + red[2][3] + red[3][3];
    float invZ = 1.0f / Z;
    msgs[n * 3 + 0] = m0 * invZ;
    msgs[n * 3 + 1] = m1 * invZ;
    msgs[n * 3 + 2] = m2 * invZ;
  }
}

// ---------------------------------------------------------------------------
// Kernel E: out MLP + 0.25*msgs + frame rotation
// ---------------------------------------------------------------------------
__global__ __launch_bounds__(256) void out_mlp(
    const float* __restrict__ nh, const float* __restrict__ dl,
    const float* __restrict__ msgs, const float* __restrict__ frames,
    const float* __restrict__ W1, const float* __restrict__ b1,
    const float* __restrict__ W2, const float* __restrict__ b2,
    float* __restrict__ out, int N)
{
  const int n0 = blockIdx.x * 4, tid = threadIdx.x;
  __shared__ float4 feat4[262];
  __shared__ float red[4][4][3];
  {
    const float* hp = nh + n0 * 256 + tid;
    feat4[tid] = make_float4(hp[0], hp[256], hp[512], hp[768]);
  }
  if (tid < 6) {
    int k = 256 + tid;
    float4 v;
    if (tid < 3) {
      v = make_float4(dl[(n0+0)*3+tid], dl[(n0+1)*3+tid],
                      dl[(n0+2)*3+tid], dl[(n0+3)*3+tid]);
    } else {
      int c = tid - 3;
      v = make_float4(msgs[(n0+0)*3+c], msgs[(n0+1)*3+c],
                      msgs[(n0+2)*3+c], msgs[(n0+3)*3+c]);
    }
    feat4[k] = v;
  }
  __syncthreads();

  float bb = b1[tid];
  float a0 = bb, a1 = bb, a2 = bb, a3 = bb;
  const float* Wp = W1 + tid;
  for (int kb = 0; kb < 256; kb += 64) {
    float w[64];
    #pragma unroll
    for (int u = 0; u < 64; ++u) w[u] = Wp[(kb + u) * 256];
    #pragma unroll
    for (int u = 0; u < 64; ++u) {
      float4 f = feat4[kb + u];
      a0 = fmaf(f.x, w[u], a0); a1 = fmaf(f.y, w[u], a1);
      a2 = fmaf(f.z, w[u], a2); a3 = fmaf(f.w, w[u], a3);
    }
  }
  #pragma unroll
  for (int k = 256; k < 262; ++k) {
    float w = Wp[k * 256];
    float4 f = feat4[k];
    a0 = fmaf(f.x, w, a0); a1 = fmaf(f.y, w, a1);
    a2 = fmaf(f.z, w, a2); a3 = fmaf(f.w, w, a3);
  }

  const float w0 = W2[tid * 3 + 0], w1 = W2[tid * 3 + 1], w2 = W2[tid * 3 + 2];
  const int wave = tid >> 6, lane = tid & 63;
  float va[4] = {fast_silu(a0), fast_silu(a1), fast_silu(a2), fast_silu(a3)};
  #pragma unroll
  for (int r = 0; r < 4; ++r) {
    float p0 = va[r] * w0, p1 = va[r] * w1, p2 = va[r] * w2;
    for (int off = 32; off; off >>= 1) {
      p0 += __shfl_down(p0, off);
      p1 += __shfl_down(p1, off);
      p2 += __shfl_down(p2, off);
    }
    if (lane == 0) { red[wave][r][0] = p0; red[wave][r][1] = p1; red[wave][r][2] = p2; }
  }
  __syncthreads();
  if (tid < 4) {
    int r = tid, n = n0 + r;
    float s0 = 0.f, s1 = 0.f, s2 = 0.f;
    #pragma unroll
    for (int w = 0; w < 4; ++w) { s0 += red[w][r][0]; s1 += red[w][r][1]; s2 += red[w][r][2]; }
    float m0 = msgs[n * 3 + 0], m1 = msgs[n * 3 + 1], m2 = msgs[n * 3 + 2];
    float v0 = s0 + b2[0] + 0.25f * m0;
    float v1 = s1 + b2[1] + 0.25f * m1;
    float v2 = s2 + b2[2] + 0.25f * m2;
    const float* fr = frames + n * 9;
    out[n * 3 + 0] = fr[0] * v0 + fr[1] * v1 + fr[2] * v2;
    out[n * 3 + 1] = fr[3] * v0 + fr[4] * v1 + fr[5] * v2;
    out[n * 3 + 2] = fr[6] * v0 + fr[7] * v1 + fr[8] * v2;
  }
}

// ---------------------------------------------------------------------------
extern "C" void kernel_launch(void* const* d_in, const int* in_sizes, int n_in,
                              void* d_out, int out_size, void* d_ws, size_t ws_size,
                              hipStream_t stream) {
  const float* h      = (const float*)d_in[0];
  const float* x_t    = (const float*)d_in[1];
  const float* x_cond = (const float*)d_in[2];
  const float* tau    = (const float*)d_in[3];
  const float* W_np1  = (const float*)d_in[4];
  const float* b_np1  = (const float*)d_in[5];
  const float* W_np2  = (const float*)d_in[6];
  const float* b_np2  = (const float*)d_in[7];
  const float* w_src  = (const float*)d_in[8];
  const float* b_src  = (const float*)d_in[9];
  const float* w_dst  = (const float*)d_in[10];
  const float* b_dst  = (const float*)d_in[11];
  const float* w_ns   = (const float*)d_in[12];
  const float* b_ns   = (const float*)d_in[13];
  const float* W_eg1  = (const float*)d_in[14];
  const float* b_eg1  = (const float*)d_in[15];
  const float* w_eg2  = (const float*)d_in[16];
  const float* b_eg2  = (const float*)d_in[17];
  const float* W_out1 = (const float*)d_in[18];
  const float* b_out1 = (const float*)d_in[19];
  const float* W_out2 = (const float*)d_in[20];
  const float* b_out2 = (const float*)d_in[21];
  float* out = (float*)d_out;

  const int N = in_sizes[1] / 3;  // 1024

  float* ws     = (float*)d_ws;
  float* frames = ws;                 // N*9
  float* dl     = frames + N * 9;     // N*3
  float* nh     = dl + N * 3;         // N*256
  float* srcv   = nh + N * 256;       // N
  float* dstv   = srcv + N;           // N
  float* nsv    = dstv + N;           // N
  float* msgs   = nsv + N;            // N*3
  float* wpk    = msgs + N * 3;       // 128*8 + 16 pad

  frames_kernel<<<N / 256 + 1, 256, 0, stream>>>(x_cond, x_t, frames, dl,
                                                 W_eg1, b_eg1, w_eg2, wpk, N);
  node_mlp<<<N / 4, 256, 0, stream>>>(h, dl, tau, W_np1, b_np1, W_np2, b_np2,
                                      w_src, b_src, w_dst, b_dst, w_ns, b_ns,
                                      nh, srcv, dstv, nsv, N);
  edge_softmax<<<N, 256, 0, stream>>>(x_t, frames, srcv, dstv, nsv,
                                      wpk, b_eg2, msgs, N);
  out_mlp<<<N / 4, 256, 0, stream>>>(nh, dl, msgs, frames,
                                     W_out1, b_out1, W_out2, b_out2, out, N);
}

// Round 7
// 61.934 us; speedup vs baseline: 1.0848x; 1.0507x over previous
//
#include <hip/hip_runtime.h>
#include <math.h>

#define DEV __device__ __forceinline__

typedef float v2f __attribute__((ext_vector_type(2)));
DEV v2f splat2(float s){ return (v2f){s, s}; }
DEV v2f pkfma(v2f a, v2f b, v2f c){ return __builtin_elementwise_fma(a, b, c); }

struct F3 { float x, y, z; };

DEV F3 mkf3(float x, float y, float z){ F3 r; r.x=x; r.y=y; r.z=z; return r; }
DEV F3 f3add(F3 a, F3 b){ return mkf3(a.x+b.x, a.y+b.y, a.z+b.z); }
DEV F3 f3sub(F3 a, F3 b){ return mkf3(a.x-b.x, a.y-b.y, a.z-b.z); }
DEV F3 f3scale(F3 a, float s){ return mkf3(a.x*s, a.y*s, a.z*s); }
DEV float f3dot(F3 a, F3 b){ return a.x*b.x + a.y*b.y + a.z*b.z; }
DEV F3 f3cross(F3 a, F3 b){
  return mkf3(a.y*b.z - a.z*b.y, a.z*b.x - a.x*b.z, a.x*b.y - a.y*b.x);
}
// reference: v / sqrt(max(sum(v*v), 1e-6)); fallback branch is dead
DEV F3 f3dir(F3 v){
  float ss = f3dot(v, v);
  float inv = 1.0f / sqrtf(fmaxf(ss, 1e-6f));
  return f3scale(v, inv);
}
DEV float fast_silu(float x){
  return x * __builtin_amdgcn_rcpf(1.0f + __expf(-x));
}
DEV float fast_sigmoid(float x){
  return __builtin_amdgcn_rcpf(1.0f + __expf(-x));
}

// ---------------------------------------------------------------------------
// Kernel B: fused {frames + delta_local} + node MLP (2 layers + 3 heads),
// 4 rows/block. Block 0 threads 128-255 additionally pack+prescale the
// edge-MLP weights into wpk.
// ---------------------------------------------------------------------------
__global__ __launch_bounds__(256) void node_mlp(
    const float* __restrict__ h, const float* __restrict__ xc,
    const float* __restrict__ xt, const float* __restrict__ tau,
    const float* __restrict__ W1, const float* __restrict__ b1,
    const float* __restrict__ W2, const float* __restrict__ b2,
    const float* __restrict__ w_src, const float* __restrict__ b_src,
    const float* __restrict__ w_dst, const float* __restrict__ b_dst,
    const float* __restrict__ w_ns, const float* __restrict__ b_ns,
    const float* __restrict__ W_eg1, const float* __restrict__ b_eg1,
    const float* __restrict__ w_eg2,
    float* __restrict__ frames, float* __restrict__ dl,
    float* __restrict__ wpk,
    float* __restrict__ nh, float* __restrict__ srcv,
    float* __restrict__ dstv, float* __restrict__ nsv, int N)
{
  const int n0 = blockIdx.x * 4, tid = threadIdx.x;
  __shared__ float4 fA[262];       // [h, dl, t_emb] transposed, 4 rows
  __shared__ float4 fB[256];       // nh1 transposed, 4 rows
  __shared__ float red[4][4][3];   // [wave][row][head]
  __shared__ float sdl[4][3];

  // ---- weight pack (block 0, threads 128..255) ----
  if (blockIdx.x == 0 && tid >= 128) {
    int j = tid - 128;
    const float nl2e = -1.44269504088896340736f;  // -log2(e)
    const float nln2 = -0.69314718055994530942f;  // -ln(2)
    wpk[j*8+0] = nl2e * W_eg1[j];
    wpk[j*8+1] = nl2e * W_eg1[128 + j];
    wpk[j*8+2] = nl2e * W_eg1[256 + j];
    wpk[j*8+3] = nl2e * W_eg1[384 + j];
    wpk[j*8+4] = nl2e * b_eg1[j];
    wpk[j*8+5] = nln2 * w_eg2[j];
    wpk[j*8+6] = 0.f; wpk[j*8+7] = 0.f;
    if (j < 16) wpk[1024 + j] = 0.f;   // pad so prefetch overrun is benign
  }

  // ---- frames + delta_local for this block's 4 rows (threads 0..3) ----
  if (tid < 4) {
    int n = n0 + tid;
    int pn = (n > 0) ? n - 1 : 0;       // prev = d[max(n-1,0)]
    int qn = (n < N - 1) ? n : N - 2;   // nxt  = d[min(n,N-2)]
    F3 prev = mkf3(xc[(pn+1)*3+0]-xc[pn*3+0], xc[(pn+1)*3+1]-xc[pn*3+1], xc[(pn+1)*3+2]-xc[pn*3+2]);
    F3 nxt  = mkf3(xc[(qn+1)*3+0]-xc[qn*3+0], xc[(qn+1)*3+1]-xc[qn*3+1], xc[(qn+1)*3+2]-xc[qn*3+2]);

    F3 tangent = f3dir(f3add(prev, nxt));
    F3 curv    = f3dir(f3sub(nxt, prev));
    float ct   = f3dot(curv, tangent);
    F3 ay      = f3dir(f3sub(curv, f3scale(tangent, ct)));
    F3 az      = f3dir(f3cross(tangent, ay));
    ay         = f3dir(f3cross(az, tangent));

    float* fr = frames + n * 9;
    fr[0] = tangent.x; fr[1] = ay.x; fr[2] = az.x;
    fr[3] = tangent.y; fr[4] = ay.y; fr[5] = az.y;
    fr[6] = tangent.z; fr[7] = ay.z; fr[8] = az.z;

    F3 delta = mkf3(xt[n*3+0]-xc[n*3+0], xt[n*3+1]-xc[n*3+1], xt[n*3+2]-xc[n*3+2]);
    float d0 = f3dot(tangent, delta), d1 = f3dot(ay, delta), d2 = f3dot(az, delta);
    dl[n*3+0] = d0; dl[n*3+1] = d1; dl[n*3+2] = d2;
    sdl[tid][0] = d0; sdl[tid][1] = d1; sdl[tid][2] = d2;
  }
  __syncthreads();

  // ---- stage activations (transposed float4) ----
  {
    const float* hp = h + n0 * 256 + tid;
    fA[tid] = make_float4(hp[0], hp[256], hp[512], hp[768]);
  }
  if (tid < 6) {
    int k = 256 + tid;
    float4 v;
    if (tid < 3) {
      v = make_float4(sdl[0][tid], sdl[1][tid], sdl[2][tid], sdl[3][tid]);
    } else {
      float t = tau[0];
      float s = (tid == 3) ? t : ((tid == 4) ? sinf(t) : cosf(t));
      v = make_float4(s, s, s, s);
    }
    fA[k] = v;
  }
  __syncthreads();

  // ---- layer 1 ----
  {
    float bb = b1[tid];
    float a0 = bb, a1 = bb, a2 = bb, a3 = bb;
    const float* Wp = W1 + tid;
    for (int kb = 0; kb < 256; kb += 64) {
      float w[64];
      #pragma unroll
      for (int u = 0; u < 64; ++u) w[u] = Wp[(kb + u) * 256];
      #pragma unroll
      for (int u = 0; u < 64; ++u) {
        float4 f = fA[kb + u];
        a0 = fmaf(f.x, w[u], a0); a1 = fmaf(f.y, w[u], a1);
        a2 = fmaf(f.z, w[u], a2); a3 = fmaf(f.w, w[u], a3);
      }
    }
    #pragma unroll
    for (int k = 256; k < 262; ++k) {
      float w = Wp[k * 256];
      float4 f = fA[k];
      a0 = fmaf(f.x, w, a0); a1 = fmaf(f.y, w, a1);
      a2 = fmaf(f.z, w, a2); a3 = fmaf(f.w, w, a3);
    }
    fB[tid] = make_float4(fast_silu(a0), fast_silu(a1), fast_silu(a2), fast_silu(a3));
  }
  __syncthreads();

  // ---- layer 2 + heads ----
  float bb = b2[tid];
  float a0 = bb, a1 = bb, a2 = bb, a3 = bb;
  const float* Wp = W2 + tid;
  for (int kb = 0; kb < 256; kb += 64) {
    float w[64];
    #pragma unroll
    for (int u = 0; u < 64; ++u) w[u] = Wp[(kb + u) * 256];
    #pragma unroll
    for (int u = 0; u < 64; ++u) {
      float4 f = fB[kb + u];
      a0 = fmaf(f.x, w[u], a0); a1 = fmaf(f.y, w[u], a1);
      a2 = fmaf(f.z, w[u], a2); a3 = fmaf(f.w, w[u], a3);
    }
  }

  const float wsv = w_src[tid], wdv = w_dst[tid], wnv = w_ns[tid];
  const int wave = tid >> 6, lane = tid & 63;
  float va[4] = {fast_silu(a0), fast_silu(a1), fast_silu(a2), fast_silu(a3)};
  #pragma unroll
  for (int r = 0; r < 4; ++r) {
    nh[(n0 + r) * 256 + tid] = va[r];
    float ps = va[r] * wsv, pd = va[r] * wdv, pn = va[r] * wnv;
    for (int off = 32; off; off >>= 1) {
      ps += __shfl_down(ps, off);
      pd += __shfl_down(pd, off);
      pn += __shfl_down(pn, off);
    }
    if (lane == 0) { red[wave][r][0] = ps; red[wave][r][1] = pd; red[wave][r][2] = pn; }
  }
  __syncthreads();
  if (tid < 4) {
    int r = tid;
    float s0 = 0.f, s1 = 0.f, s2 = 0.f;
    #pragma unroll
    for (int w = 0; w < 4; ++w) { s0 += red[w][r][0]; s1 += red[w][r][1]; s2 += red[w][r][2]; }
    srcv[n0 + r] = s0 + b_src[0];
    dstv[n0 + r] = s1 + b_dst[0];
    nsv[n0 + r]  = fast_sigmoid(s2 + b_ns[0]);
  }
}

// ---------------------------------------------------------------------------
// Kernel D: fused edge MLP + softmax + aggregation.
// One block (256 thr, 4 waves) per row n; 4 edges/thread as 2 v2f chains
// with EXPLICIT packed fma (v_pk_fma_f32). Weights uniform (SGPR),
// software-pipelined 1 chunk (2 j) ahead.
// Per j per 2 edges: 7 pk-VALU + 4 trans; zero LDS in the loop.
// ---------------------------------------------------------------------------
__global__ __launch_bounds__(256) void edge_softmax(
    const float* __restrict__ x_t, const float* __restrict__ frames,
    const float* __restrict__ srcv, const float* __restrict__ dstv,
    const float* __restrict__ nsv,
    const float* __restrict__ wpk, const float* __restrict__ b_eg2,
    float* __restrict__ msgs, int N)
{
  const int n = blockIdx.x, tid = threadIdx.x;
  __shared__ float redmax[4];
  __shared__ float red[4][4];

  // row-uniform data -> scalar loads
  const float f0 = frames[n*9+0], f1 = frames[n*9+1], f2 = frames[n*9+2],
              f3_ = frames[n*9+3], f4 = frames[n*9+4], f5 = frames[n*9+5],
              f6 = frames[n*9+6], f7 = frames[n*9+7], f8 = frames[n*9+8];
  const float x0 = x_t[n*3+0], x1 = x_t[n*3+1], x2 = x_t[n*3+2];
  const float sn = srcv[n];
  const float b2v = b_eg2[0];

  // ---- phase 0: 4 edges' rel_local + dist; prefetch dst/ns ----
  float r0s[4], r1s[4], r2s[4], dds[4], dst_r[4], ns_r[4];
  #pragma unroll
  for (int e = 0; e < 4; ++e) {
    const int m = e * 256 + tid;
    dst_r[e] = dstv[m];
    ns_r[e]  = nsv[m];
    float rx = x_t[m * 3 + 0] - x0;
    float ry = x_t[m * 3 + 1] - x1;
    float rz = x_t[m * 3 + 2] - x2;
    r0s[e] = f0 * rx + f3_ * ry + f6 * rz;
    r1s[e] = f1 * rx + f4 * ry + f7 * rz;
    r2s[e] = f2 * rx + f5 * ry + f8 * rz;
    dds[e] = sqrtf(r0s[e]*r0s[e] + r1s[e]*r1s[e] + r2s[e]*r2s[e]);
  }
  const v2f r0A = {r0s[0], r0s[1]}, r0B = {r0s[2], r0s[3]};
  const v2f r1A = {r1s[0], r1s[1]}, r1B = {r1s[2], r1s[3]};
  const v2f r2A = {r2s[0], r2s[1]}, r2B = {r2s[2], r2s[3]};
  const v2f ddA = {dds[0], dds[1]}, ddB = {dds[2], dds[3]};

  v2f accA = {0.f, 0.f}, accB = {0.f, 0.f};

  // ---- phase 1: edge-MLP logits; packed fma + pipelined uniform loads ----
  const float4* __restrict__ wp4 = (const float4*)wpk;

#define J_STEP(WA, WB)                                                        \
  {                                                                           \
    v2f wxx = splat2(WA.x), wyy = splat2(WA.y);                               \
    v2f wzz = splat2(WA.z), wdd = splat2(WA.w);                               \
    v2f wbb = splat2(WB.x), w22 = splat2(WB.y);                               \
    v2f tpA = pkfma(wdd, ddA, wbb);                                           \
    tpA = pkfma(wzz, r2A, tpA);                                               \
    tpA = pkfma(wyy, r1A, tpA);                                               \
    tpA = pkfma(wxx, r0A, tpA);                                               \
    v2f tpB = pkfma(wdd, ddB, wbb);                                           \
    tpB = pkfma(wzz, r2B, tpB);                                               \
    tpB = pkfma(wyy, r1B, tpB);                                               \
    tpB = pkfma(wxx, r0B, tpB);                                               \
    v2f eA, eB;                                                               \
    eA.x = __builtin_amdgcn_exp2f(tpA.x); eA.y = __builtin_amdgcn_exp2f(tpA.y); \
    eB.x = __builtin_amdgcn_exp2f(tpB.x); eB.y = __builtin_amdgcn_exp2f(tpB.y); \
    v2f opA = eA + splat2(1.0f);                                              \
    v2f opB = eB + splat2(1.0f);                                              \
    v2f sgA, sgB;                                                             \
    sgA.x = __builtin_amdgcn_rcpf(opA.x); sgA.y = __builtin_amdgcn_rcpf(opA.y); \
    sgB.x = __builtin_amdgcn_rcpf(opB.x); sgB.y = __builtin_amdgcn_rcpf(opB.y); \
    accA = pkfma(w22 * tpA, sgA, accA);                                       \
    accB = pkfma(w22 * tpB, sgB, accB);                                       \
  }

  // chunk = 2 j's (4 float4 uniform loads), prefetched one chunk ahead
  float4 ca0 = wp4[0], cb0 = wp4[1], ca1 = wp4[2], cb1 = wp4[3];
  for (int c = 0; c < 64; ++c) {
    float4 na0 = wp4[(c + 1) * 4 + 0];
    float4 nb0 = wp4[(c + 1) * 4 + 1];
    float4 na1 = wp4[(c + 1) * 4 + 2];
    float4 nb1 = wp4[(c + 1) * 4 + 3];
    J_STEP(ca0, cb0)
    J_STEP(ca1, cb1)
    ca0 = na0; cb0 = nb0; ca1 = na1; cb1 = nb1;
  }
#undef J_STEP

  float l[4];
  float lmax = -3.4e38f;
  float accs[4] = {accA.x, accA.y, accB.x, accB.y};
  #pragma unroll
  for (int e = 0; e < 4; ++e) {
    const int m = e * 256 + tid;
    float lg = sn + dst_r[e] + b2v + accs[e];
    if (m == n) lg = -10000.0f;
    l[e] = lg;
    lmax = fmaxf(lmax, lg);
  }

  // ---- block max reduce (4 waves) ----
  for (int off = 32; off; off >>= 1) lmax = fmaxf(lmax, __shfl_down(lmax, off));
  const int wave = tid >> 6, lane = tid & 63;
  if (lane == 0) redmax[wave] = lmax;
  __syncthreads();
  const float mx = fmaxf(fmaxf(redmax[0], redmax[1]), fmaxf(redmax[2], redmax[3]));

  // ---- phase 2: softmax + aggregation ----
  float r0all[4] = {r0A.x, r0A.y, r0B.x, r0B.y};
  float r1all[4] = {r1A.x, r1A.y, r1B.x, r1B.y};
  float r2all[4] = {r2A.x, r2A.y, r2B.x, r2B.y};
  float sum = 0.f, a0 = 0.f, a1 = 0.f, a2 = 0.f;
  #pragma unroll
  for (int e = 0; e < 4; ++e) {
    float ee = __expf(l[e] - mx);     // diag underflows to 0
    sum += ee;
    float w = ee * ns_r[e];
    a0 = fmaf(w, r0all[e], a0);
    a1 = fmaf(w, r1all[e], a1);
    a2 = fmaf(w, r2all[e], a2);
  }
  for (int off = 32; off; off >>= 1) {
    sum += __shfl_down(sum, off);
    a0 += __shfl_down(a0, off);
    a1 += __shfl_down(a1, off);
    a2 += __shfl_down(a2, off);
  }
  if (lane == 0) { red[wave][0] = sum; red[wave][1] = a0; red[wave][2] = a1; red[wave][3] = a2; }
  __syncthreads();
  if (tid == 0) {
    float Z  = red[0][0] + red[1][0] + red[2][0] + red[3][0];
    float m0 = red[0][1] + red[1][1] + red[2][1] + red[3][1];
    float m1 = red[0][2] + red[1][2] + red[2][2] + red[3][2];
    float m2 = red[0][3] + red[1][3] + red[2][3] + red[3][3];
    float invZ = 1.0f / Z;
    msgs[n * 3 + 0] = m0 * invZ;
    msgs[n * 3 + 1] = m1 * invZ;
    msgs[n * 3 + 2] = m2 * invZ;
  }
}

// ---------------------------------------------------------------------------
// Kernel E: out MLP + 0.25*msgs + frame rotation
// ---------------------------------------------------------------------------
__global__ __launch_bounds__(256) void out_mlp(
    const float* __restrict__ nh, const float* __restrict__ dl,
    const float* __restrict__ msgs, const float* __restrict__ frames,
    const float* __restrict__ W1, const float* __restrict__ b1,
    const float* __restrict__ W2, const float* __restrict__ b2,
    float* __restrict__ out, int N)
{
  const int n0 = blockIdx.x * 4, tid = threadIdx.x;
  __shared__ float4 feat4[262];
  __shared__ float red[4][4][3];
  {
    const float* hp = nh + n0 * 256 + tid;
    feat4[tid] = make_float4(hp[0], hp[256], hp[512], hp[768]);
  }
  if (tid < 6) {
    int k = 256 + tid;
    float4 v;
    if (tid < 3) {
      v = make_float4(dl[(n0+0)*3+tid], dl[(n0+1)*3+tid],
                      dl[(n0+2)*3+tid], dl[(n0+3)*3+tid]);
    } else {
      int c = tid - 3;
      v = make_float4(msgs[(n0+0)*3+c], msgs[(n0+1)*3+c],
                      msgs[(n0+2)*3+c], msgs[(n0+3)*3+c]);
    }
    feat4[k] = v;
  }
  __syncthreads();

  float bb = b1[tid];
  float a0 = bb, a1 = bb, a2 = bb, a3 = bb;
  const float* Wp = W1 + tid;
  for (int kb = 0; kb < 256; kb += 64) {
    float w[64];
    #pragma unroll
    for (int u = 0; u < 64; ++u) w[u] = Wp[(kb + u) * 256];
    #pragma unroll
    for (int u = 0; u < 64; ++u) {
      float4 f = feat4[kb + u];
      a0 = fmaf(f.x, w[u], a0); a1 = fmaf(f.y, w[u], a1);
      a2 = fmaf(f.z, w[u], a2); a3 = fmaf(f.w, w[u], a3);
    }
  }
  #pragma unroll
  for (int k = 256; k < 262; ++k) {
    float w = Wp[k * 256];
    float4 f = feat4[k];
    a0 = fmaf(f.x, w, a0); a1 = fmaf(f.y, w, a1);
    a2 = fmaf(f.z, w, a2); a3 = fmaf(f.w, w, a3);
  }

  const float w0 = W2[tid * 3 + 0], w1 = W2[tid * 3 + 1], w2 = W2[tid * 3 + 2];
  const int wave = tid >> 6, lane = tid & 63;
  float va[4] = {fast_silu(a0), fast_silu(a1), fast_silu(a2), fast_silu(a3)};
  #pragma unroll
  for (int r = 0; r < 4; ++r) {
    float p0 = va[r] * w0, p1 = va[r] * w1, p2 = va[r] * w2;
    for (int off = 32; off; off >>= 1) {
      p0 += __shfl_down(p0, off);
      p1 += __shfl_down(p1, off);
      p2 += __shfl_down(p2, off);
    }
    if (lane == 0) { red[wave][r][0] = p0; red[wave][r][1] = p1; red[wave][r][2] = p2; }
  }
  __syncthreads();
  if (tid < 4) {
    int r = tid, n = n0 + r;
    float s0 = 0.f, s1 = 0.f, s2 = 0.f;
    #pragma unroll
    for (int w = 0; w < 4; ++w) { s0 += red[w][r][0]; s1 += red[w][r][1]; s2 += red[w][r][2]; }
    float m0 = msgs[n * 3 + 0], m1 = msgs[n * 3 + 1], m2 = msgs[n * 3 + 2];
    float v0 = s0 + b2[0] + 0.25f * m0;
    float v1 = s1 + b2[1] + 0.25f * m1;
    float v2 = s2 + b2[2] + 0.25f * m2;
    const float* fr = frames + n * 9;
    out[n * 3 + 0] = fr[0] * v0 + fr[1] * v1 + fr[2] * v2;
    out[n * 3 + 1] = fr[3] * v0 + fr[4] * v1 + fr[5] * v2;
    out[n * 3 + 2] = fr[6] * v0 + fr[7] * v1 + fr[8] * v2;
  }
}

// ---------------------------------------------------------------------------
extern "C" void kernel_launch(void* const* d_in, const int* in_sizes, int n_in,
                              void* d_out, int out_size, void* d_ws, size_t ws_size,
                              hipStream_t stream) {
  const float* h      = (const float*)d_in[0];
  const float* x_t    = (const float*)d_in[1];
  const float* x_cond = (const float*)d_in[2];
  const float* tau    = (const float*)d_in[3];
  const float* W_np1  = (const float*)d_in[4];
  const float* b_np1  = (const float*)d_in[5];
  const float* W_np2  = (const float*)d_in[6];
  const float* b_np2  = (const float*)d_in[7];
  const float* w_src  = (const float*)d_in[8];
  const float* b_src  = (const float*)d_in[9];
  const float* w_dst  = (const float*)d_in[10];
  const float* b_dst  = (const float*)d_in[11];
  const float* w_ns   = (const float*)d_in[12];
  const float* b_ns   = (const float*)d_in[13];
  const float* W_eg1  = (const float*)d_in[14];
  const float* b_eg1  = (const float*)d_in[15];
  const float* w_eg2  = (const float*)d_in[16];
  const float* b_eg2  = (const float*)d_in[17];
  const float* W_out1 = (const float*)d_in[18];
  const float* b_out1 = (const float*)d_in[19];
  const float* W_out2 = (const float*)d_in[20];
  const float* b_out2 = (const float*)d_in[21];
  float* out = (float*)d_out;

  const int N = in_sizes[1] / 3;  // 1024

  float* ws     = (float*)d_ws;
  float* frames = ws;                 // N*9
  float* dl     = frames + N * 9;     // N*3
  float* nh     = dl + N * 3;         // N*256
  float* srcv   = nh + N * 256;       // N
  float* dstv   = srcv + N;           // N
  float* nsv    = dstv + N;           // N
  float* msgs   = nsv + N;            // N*3
  float* wpk    = msgs + N * 3;       // 128*8 + 16 pad

  node_mlp<<<N / 4, 256, 0, stream>>>(h, x_cond, x_t, tau,
                                      W_np1, b_np1, W_np2, b_np2,
                                      w_src, b_src, w_dst, b_dst, w_ns, b_ns,
                                      W_eg1, b_eg1, w_eg2,
                                      frames, dl, wpk,
                                      nh, srcv, dstv, nsv, N);
  edge_softmax<<<N, 256, 0, stream>>>(x_t, frames, srcv, dstv, nsv,
                                      wpk, b_eg2, msgs, N);
  out_mlp<<<N / 4, 256, 0, stream>>>(nh, dl, msgs, frames,
                                     W_out1, b_out1, W_out2, b_out2, out, N);
}